// Round 6
// baseline (323.081 us; speedup 1.0000x reference)
//
#include <hip/hip_runtime.h>

// OptPosEncVol R7: sorted trilinear gather, LDS staging, CHUNKED bin work.
// R6 post-mortem: LDS staging killed gather traffic (FETCH 307MB->11MB) but
// block-per-bin = 729 active blocks, occupancy 12.7%, 45-iter serial loops ->
// 86.7us latency-bound. R7: work list of (bin, 256-pt chunk) items (~2900),
// built in hist_scan's last block; grid=6144 w/ early exit. 4 blocks/CU
// concurrent (34KB LDS), 16-iter loops -> balance + latency hiding.

#define CODE_NUM 64
#define CODE_CHANNEL 64
#define TABLE (CODE_NUM * CODE_NUM * CODE_NUM)  // 262144
#define NBINS 4096                              // 16^3 coarse cells (4-cell bricks)
#define SCAT_PTS 1024                           // points per scatter block
#define SCAT_PPT 4                              // points per thread (1024/256)
#define TBLOCKS (TABLE / 64)                    // 4096 transpose tiles
#define LROW 68                                 // LDS row stride floats (272B pad)
#define CHUNK 256                               // points per interp work item
#define MAXITEMS 8192

typedef float f4_t __attribute__((ext_vector_type(4)));

__device__ __forceinline__ void nt_store_f4(float* p, float x, float y, float z, float w) {
    f4_t v = {x, y, z, w};
    __builtin_nontemporal_store(v, (f4_t*)p);
}

// ---------------- aux: init ----------------
__global__ __launch_bounds__(256) void init_k(int* __restrict__ hist, int* __restrict__ bbox,
                                              int* __restrict__ done, int* __restrict__ nitems) {
    const int t = blockIdx.x * 256 + threadIdx.x;
    for (int i = t; i < NBINS; i += gridDim.x * 256) hist[i] = 0;
    if (t == 0) {
        bbox[0] = 0x7fffffff; bbox[1] = (int)0x80000000;  // ymin, ymax
        bbox[2] = 0x7fffffff; bbox[3] = (int)0x80000000;  // zmin, zmax
        done[0] = 0;
        nitems[0] = 0;
    }
}

__device__ __forceinline__ int cell_bin(float x, float y, float z,
                                        int& ix, int& iy, int& iz) {
    ix = (int)floorf((x + 1.0f) * ((CODE_NUM - 1) * 0.5f));
    iy = (int)floorf((y + 1.0f) * ((CODE_NUM - 1) * 0.5f));
    iz = (int)floorf((z + 1.0f) * ((CODE_NUM - 1) * 0.5f));
    const int cx = min(max(ix, 0), 63) >> 2;
    const int cy = min(max(iy, 0), 63) >> 2;
    const int cz = min(max(iz, 0), 63) >> 2;
    return cx | (cy << 4) | (cz << 8);
}

// ---------------- pass 1: histogram + bbox; LAST block scans + builds work list ----------------
__global__ __launch_bounds__(256) void hist_scan_k(const float* __restrict__ coords, int npoints,
                                                   int* __restrict__ hist, int* __restrict__ bbox,
                                                   int* __restrict__ done,
                                                   int* __restrict__ cursor,
                                                   int* __restrict__ starts,
                                                   int* __restrict__ nitems,
                                                   int2* __restrict__ items) {
    __shared__ int lh[NBINS];
    __shared__ int lb[4];
    __shared__ int lastflag;
    __shared__ int wbase[4];
    for (int i = threadIdx.x; i < NBINS; i += 256) lh[i] = 0;
    if (threadIdx.x == 0) {
        lb[0] = 0x7fffffff; lb[1] = (int)0x80000000;
        lb[2] = 0x7fffffff; lb[3] = (int)0x80000000;
        lastflag = 0;
    }
    __syncthreads();
    int ymin = 0x7fffffff, ymax = (int)0x80000000;
    int zmin = 0x7fffffff, zmax = (int)0x80000000;
    const int stride = gridDim.x * 256;
    for (int p = blockIdx.x * 256 + threadIdx.x; p < npoints; p += stride) {
        const float x = coords[p * 3 + 0];
        const float y = coords[p * 3 + 1];
        const float z = coords[p * 3 + 2];
        int ix, iy, iz;
        const int bin = cell_bin(x, y, z, ix, iy, iz);
        atomicAdd(&lh[bin], 1);
        ymin = min(ymin, iy); ymax = max(ymax, iy);
        zmin = min(zmin, iz); zmax = max(zmax, iz);
    }
    atomicMin(&lb[0], ymin); atomicMax(&lb[1], ymax);
    atomicMin(&lb[2], zmin); atomicMax(&lb[3], zmax);
    __syncthreads();
    for (int i = threadIdx.x; i < NBINS; i += 256) {
        const int c = lh[i];
        if (c) atomicAdd(&hist[i], c);
    }
    if (threadIdx.x == 0) {
        atomicMin(&bbox[0], lb[0]); atomicMax(&bbox[1], lb[1]);
        atomicMin(&bbox[2], lb[2]); atomicMax(&bbox[3], lb[3]);
    }
    __threadfence();
    __syncthreads();
    if (threadIdx.x == 0) {
        const int r = atomicAdd(done, 1);
        if (r == (int)gridDim.x - 1) lastflag = 1;
    }
    __syncthreads();
    if (!lastflag) return;

    // ---- scan + work-list build (only the last-finishing block) ----
    const int t = threadIdx.x;
    int h[16];
    int s = 0;
#pragma unroll
    for (int j = 0; j < 16; ++j) {
        h[j] = atomicAdd(&hist[t * 16 + j], 0);
        s += h[j];
    }
    const int lane = t & 63, wv = t >> 6;
    int inc = s;
#pragma unroll
    for (int d = 1; d < 64; d <<= 1) {
        const int u = __shfl_up(inc, d, 64);
        if (lane >= d) inc += u;
    }
    if (lane == 63) wbase[wv] = inc;
    __syncthreads();
    int wex = 0;
#pragma unroll
    for (int w = 0; w < 4; ++w)
        if (w < wv) wex += wbase[w];
    int run = wex + (inc - s);  // exclusive base for this thread's 16 bins
#pragma unroll
    for (int j = 0; j < 16; ++j) {
        const int bin = t * 16 + j;
        cursor[bin] = run;
        starts[bin] = run;
        const int c = h[j];
        if (c > 0) {
            const int nch = (c + CHUNK - 1) / CHUNK;
            const int base = atomicAdd(nitems, nch);
            for (int k = 0; k < nch; ++k)
                items[base + k] = make_int2(bin, run + k * CHUNK);
        }
        run += c;
    }
    if (t == 255) starts[NBINS] = npoints;
}

// ---------------- pass 2 (fused): transpose_bb (blocks 0..4095) + scatter (rest) ----------------
__global__ __launch_bounds__(256) void mid_fused_k(const float* __restrict__ src,
                                                   float* __restrict__ dst,
                                                   const int* __restrict__ bbox,
                                                   const float* __restrict__ coords, int npoints,
                                                   int* __restrict__ cursor,
                                                   float4* __restrict__ sorted) {
    __shared__ int smem[64 * 65];

    if (blockIdx.x < TBLOCKS) {
        const int t0 = blockIdx.x * 64;
        const int y = (t0 >> 6) & 63;
        const int z = t0 >> 12;
        if (y < bbox[0] || y > bbox[1] + 1 || z < bbox[2] || z > bbox[3] + 1) return;

        float* tile = (float*)smem;
        const int j = threadIdx.x;
#pragma unroll
        for (int i = 0; i < 4; ++i) {
            const int q = (i << 8) | j;
            const int c = q >> 4;
            const int tc4 = q & 15;
            const float4 v = *(const float4*)(src + (size_t)c * TABLE + t0 + (tc4 << 2));
            tile[((tc4 << 2) + 0) * 65 + c] = v.x;
            tile[((tc4 << 2) + 1) * 65 + c] = v.y;
            tile[((tc4 << 2) + 2) * 65 + c] = v.z;
            tile[((tc4 << 2) + 3) * 65 + c] = v.w;
        }
        __syncthreads();
#pragma unroll
        for (int i = 0; i < 4; ++i) {
            const int q = (i << 8) | j;
            const int t = q >> 4;
            const int c4 = q & 15;
            nt_store_f4(dst + (size_t)(t0 + t) * 64 + (c4 << 2),
                        tile[t * 65 + (c4 << 2) + 0],
                        tile[t * 65 + (c4 << 2) + 1],
                        tile[t * 65 + (c4 << 2) + 2],
                        tile[t * 65 + (c4 << 2) + 3]);
        }
    } else {
        int* lcount = smem;
        for (int i = threadIdx.x; i < NBINS; i += 256) lcount[i] = 0;
        __syncthreads();

        const int p0 = (int)(blockIdx.x - TBLOCKS) * SCAT_PTS;
        float px[SCAT_PPT], py[SCAT_PPT], pz[SCAT_PPT];
        int pbin[SCAT_PPT], prank[SCAT_PPT];

#pragma unroll
        for (int i = 0; i < SCAT_PPT; ++i) {
            const int p = p0 + (i << 8) + (int)threadIdx.x;
            pbin[i] = -1;
            if (p < npoints) {
                const float x = coords[p * 3 + 0];
                const float y = coords[p * 3 + 1];
                const float z = coords[p * 3 + 2];
                int ix, iy, iz;
                const int bin = cell_bin(x, y, z, ix, iy, iz);
                px[i] = x; py[i] = y; pz[i] = z;
                pbin[i] = bin;
                prank[i] = atomicAdd(&lcount[bin], 1);
            }
        }
        __syncthreads();

        for (int i = threadIdx.x; i < NBINS; i += 256) {
            const int c = lcount[i];
            if (c) lcount[i] = atomicAdd(&cursor[i], c);
        }
        __syncthreads();

#pragma unroll
        for (int i = 0; i < SCAT_PPT; ++i) {
            if (pbin[i] >= 0) {
                const int p = p0 + (i << 8) + (int)threadIdx.x;
                const int slot = lcount[pbin[i]] + prank[i];
                sorted[slot] = make_float4(px[i], py[i], pz[i], __int_as_float(p));
            }
        }
    }
}

// ---------------- pass 3: chunked block-per-work-item interpolation from LDS ----------------
__global__ __launch_bounds__(256) void interp_chunk_k(const float4* __restrict__ sorted,
                                                      const float* __restrict__ table,
                                                      const int* __restrict__ starts,
                                                      const int* __restrict__ nitems,
                                                      const int2* __restrict__ items,
                                                      float* __restrict__ out) {
    unsigned bid = blockIdx.x;
    const unsigned nb = gridDim.x;
    if ((nb & 7u) == 0u) {  // XCD-chunked swizzle: same-bin chunks stay on one XCD
        const unsigned c = nb >> 3;
        bid = (bid & 7u) * c + (bid >> 3);
    }
    if ((int)bid >= nitems[0]) return;
    const int2 it = items[bid];
    const int bin = it.x;
    const int s = it.y;
    const int e = min(starts[bin + 1], s + CHUNK);

    const int x0 = (bin & 15) << 2;
    const int y0 = ((bin >> 4) & 15) << 2;
    const int z0 = (bin >> 8) << 2;

    __shared__ float lds[125 * LROW];  // 34 KB -> 4 blocks/CU

    // Stage the bin's 5x5x5 x 64ch region: 125 rows x 16 float4, x-contiguous src.
    // Boundary bins read a few rows past the region (within ws); never consumed.
    const f4_t* tt4 = (const f4_t*)table;
    for (int i = threadIdx.x; i < 125 * 16; i += 256) {
        const int row = i >> 4, o = i & 15;
        const int dx = row % 5;
        const int seg = row / 5;             // dz*5+dy
        const int dy = seg % 5, dz = seg / 5;
        const int cell = (z0 + dz) * (CODE_NUM * CODE_NUM) + (y0 + dy) * CODE_NUM + (x0 + dx);
        *(f4_t*)&lds[row * LROW + (o << 2)] = tt4[(size_t)cell * 16 + o];
    }
    __syncthreads();

    const int lane = threadIdx.x & 63;
    const int wv = threadIdx.x >> 6;
    const int sub = lane >> 4;       // point slot within wave (0..3)
    const int cg = lane & 15;        // channel group

    for (int p = s + wv * 4 + sub; p < e; p += 16) {
        const float4 s4 = sorted[p];
        const int op = __float_as_int(s4.w);

        const float sx = (s4.x + 1.0f) * ((CODE_NUM - 1) * 0.5f);
        const float sy = (s4.y + 1.0f) * ((CODE_NUM - 1) * 0.5f);
        const float sz = (s4.z + 1.0f) * ((CODE_NUM - 1) * 0.5f);
        const float fx = floorf(sx), fy = floorf(sy), fz = floorf(sz);
        const float rx = sx - fx, ry = sy - fy, rz = sz - fz;
        const int ix = (int)fx, iy = (int)fy, iz = (int)fz;
        const int r0 = ((iz - z0) * 5 + (iy - y0)) * 5 + (ix - x0);

        const float wx[2] = {1.0f - rx, rx};
        const float wy[2] = {1.0f - ry, ry};
        const float wz[2] = {1.0f - rz, rz};

        float4 acc = make_float4(0.f, 0.f, 0.f, 0.f);
#pragma unroll
        for (int k = 0; k < 8; ++k) {
            const int a = k & 1, b = (k >> 1) & 1, c = (k >> 2) & 1;
            const int row = r0 + a + 5 * b + 25 * c;
            const float w = wx[a] * wy[b] * wz[c];
            const float4 v = *(const float4*)&lds[row * LROW + (cg << 2)];
            acc.x = fmaf(w, v.x, acc.x);
            acc.y = fmaf(w, v.y, acc.y);
            acc.z = fmaf(w, v.z, acc.z);
            acc.w = fmaf(w, v.w, acc.w);
        }
        nt_store_f4(out + (size_t)op * CODE_CHANNEL + (cg << 2), acc.x, acc.y, acc.z, acc.w);
    }
}

// ---------------- legacy paths (smaller workspace tiers) ----------------
__global__ __launch_bounds__(256) void transpose_k(const float* __restrict__ src,
                                                   float* __restrict__ dst) {
    __shared__ float tile[64 * 65];
    const int t0 = blockIdx.x * 64;
    const int j = threadIdx.x;
#pragma unroll
    for (int i = 0; i < 4; ++i) {
        const int q = (i << 8) | j;
        const int c = q >> 4;
        const int tc4 = q & 15;
        const float4 v = *(const float4*)(src + (size_t)c * TABLE + t0 + (tc4 << 2));
        tile[((tc4 << 2) + 0) * 65 + c] = v.x;
        tile[((tc4 << 2) + 1) * 65 + c] = v.y;
        tile[((tc4 << 2) + 2) * 65 + c] = v.z;
        tile[((tc4 << 2) + 3) * 65 + c] = v.w;
    }
    __syncthreads();
#pragma unroll
    for (int i = 0; i < 4; ++i) {
        const int q = (i << 8) | j;
        const int t = q >> 4;
        const int c4 = q & 15;
        float4 v;
        v.x = tile[t * 65 + (c4 << 2) + 0];
        v.y = tile[t * 65 + (c4 << 2) + 1];
        v.z = tile[t * 65 + (c4 << 2) + 2];
        v.w = tile[t * 65 + (c4 << 2) + 3];
        *(float4*)(dst + (size_t)(t0 + t) * 64 + (c4 << 2)) = v;
    }
}

__global__ __launch_bounds__(256) void interp4_k(const float* __restrict__ coords,
                                                 const float* __restrict__ table,
                                                 const int* __restrict__ idxp,
                                                 float* __restrict__ out,
                                                 int npoints) {
    const unsigned tid = blockIdx.x * 256u + threadIdx.x;
    const int lane = threadIdx.x & 63;
    const int sub = lane >> 4;
    const int cg = lane & 15;
    const int p = (int)((tid >> 6) * 4u + (unsigned)sub);
    if (p >= npoints) return;

    const int offset = idxp[0] * TABLE;
    const float sx = (coords[p * 3 + 0] + 1.0f) * ((CODE_NUM - 1) * 0.5f);
    const float sy = (coords[p * 3 + 1] + 1.0f) * ((CODE_NUM - 1) * 0.5f);
    const float sz = (coords[p * 3 + 2] + 1.0f) * ((CODE_NUM - 1) * 0.5f);
    const float fx = floorf(sx), fy = floorf(sy), fz = floorf(sz);
    const float rx = sx - fx, ry = sy - fy, rz = sz - fz;
    const int ix = (int)fx, iy = (int)fy, iz = (int)fz;
    const int base = offset + ix + iy * CODE_NUM + iz * (CODE_NUM * CODE_NUM);
    const float wx[2] = {1.0f - rx, rx};
    const float wy[2] = {1.0f - ry, ry};
    const float wz[2] = {1.0f - rz, rz};
    const char* tp = (const char*)table;
    const int cgoff = cg << 4;
    float4 acc = make_float4(0.f, 0.f, 0.f, 0.f);
#pragma unroll
    for (int k = 0; k < 8; ++k) {
        const int a = k & 1, b = (k >> 1) & 1, c = (k >> 2) & 1;
        const int idx = base + a + b * CODE_NUM + c * (CODE_NUM * CODE_NUM);
        const float w = wx[a] * wy[b] * wz[c];
        const float4 v = *(const float4*)(tp + ((size_t)(unsigned)(idx << 8) + cgoff));
        acc.x = fmaf(w, v.x, acc.x);
        acc.y = fmaf(w, v.y, acc.y);
        acc.z = fmaf(w, v.z, acc.z);
        acc.w = fmaf(w, v.w, acc.w);
    }
    *(float4*)(out + (size_t)p * CODE_CHANNEL + (cg << 2)) = acc;
}

__global__ __launch_bounds__(256) void interp_fallback_k(const float* __restrict__ coords,
                                                         const float* __restrict__ table,
                                                         const int* __restrict__ idxp,
                                                         float* __restrict__ out,
                                                         int npoints) {
    const int p = (int)((blockIdx.x * 256u + threadIdx.x) >> 6);
    const int lane = threadIdx.x & 63;
    if (p >= npoints) return;
    const int offset = idxp[0] * TABLE;
    const float sx = (coords[p * 3 + 0] + 1.0f) * ((CODE_NUM - 1) * 0.5f);
    const float sy = (coords[p * 3 + 1] + 1.0f) * ((CODE_NUM - 1) * 0.5f);
    const float sz = (coords[p * 3 + 2] + 1.0f) * ((CODE_NUM - 1) * 0.5f);
    const float fx = floorf(sx), fy = floorf(sy), fz = floorf(sz);
    const float rx = sx - fx, ry = sy - fy, rz = sz - fz;
    const int base = offset + (int)fx + (int)fy * CODE_NUM + (int)fz * (CODE_NUM * CODE_NUM);
    const float wx[2] = {1.0f - rx, rx};
    const float wy[2] = {1.0f - ry, ry};
    const float wz[2] = {1.0f - rz, rz};
    float acc = 0.0f;
#pragma unroll
    for (int k = 0; k < 8; ++k) {
        const int a = k & 1, b = (k >> 1) & 1, c = (k >> 2) & 1;
        const int idx = base + a + b * CODE_NUM + c * (CODE_NUM * CODE_NUM);
        acc = fmaf(wx[a] * wy[b] * wz[c], table[(size_t)lane * TABLE + idx], acc);
    }
    out[(size_t)p * CODE_CHANNEL + lane] = acc;
}

extern "C" void kernel_launch(void* const* d_in, const int* in_sizes, int n_in,
                              void* d_out, int out_size, void* d_ws, size_t ws_size,
                              hipStream_t stream) {
    const float* coords = (const float*)d_in[0];
    const float* code   = (const float*)d_in[1];
    const int*   idxp   = (const int*)d_in[2];
    float* out = (float*)d_out;

    const int npoints = in_sizes[0] / 3;  // 524288
    const size_t tbytes = (size_t)TABLE * CODE_CHANNEL * sizeof(float);  // 64 MB
    const size_t sbytes = (size_t)npoints * sizeof(float4);              // 8 MB
    // hist + cursor + starts(+1) + bbox + done + nitems + items(int2)
    const size_t abytes = (size_t)(3 * NBINS + 1 + 4 + 1 + 1 + 16) * sizeof(int)
                        + (size_t)MAXITEMS * sizeof(int2);
    const size_t need = tbytes + sbytes + abytes;

    if (ws_size >= need) {
        char* w = (char*)d_ws;
        float*  tt     = (float*)w;
        float4* sorted = (float4*)(w + tbytes);
        int*    hist   = (int*)(w + tbytes + sbytes);
        int*    cursor = hist + NBINS;
        int*    starts = cursor + NBINS;
        int*    bbox   = starts + NBINS + 1;
        int*    done   = bbox + 4;
        int*    nitems = done + 1;
        int2*   items  = (int2*)(nitems + 9);  // 8B-aligned (offset from ws base is aligned)

        const int nscat = (npoints + SCAT_PTS - 1) / SCAT_PTS;
        const int nint = NBINS + (npoints + CHUNK - 1) / CHUNK;  // worst-case items (6144)

        init_k<<<16, 256, 0, stream>>>(hist, bbox, done, nitems);
        hist_scan_k<<<128, 256, 0, stream>>>(coords, npoints, hist, bbox, done,
                                             cursor, starts, nitems, items);
        mid_fused_k<<<TBLOCKS + nscat, 256, 0, stream>>>(code, tt, bbox,
                                                         coords, npoints, cursor, sorted);
        interp_chunk_k<<<nint, 256, 0, stream>>>(sorted, tt, starts, nitems, items, out);
    } else if (ws_size >= tbytes) {
        float* tt = (float*)d_ws;
        transpose_k<<<TABLE / 64, 256, 0, stream>>>(code, tt);
        interp4_k<<<(npoints + 15) / 16, 256, 0, stream>>>(coords, tt, idxp, out, npoints);
    } else {
        interp_fallback_k<<<(npoints + 3) / 4, 256, 0, stream>>>(coords, code, idxp, out, npoints);
    }
}

// Round 7
// 273.408 us; speedup vs baseline: 1.1817x; 1.1817x over previous
//
#include <hip/hip_runtime.h>

// OptPosEncVol R8: sorted trilinear gather, LDS staging, FAT 512-thread bins.
// R7 post-mortem: chunking multiplied staging (23->93MB, 2000 loads per 180pts)
// and regressed (87->105us). R8 keeps one block per bin (stage ONCE) but uses
// 512 threads: 34KB LDS -> 4 blocks/CU = 32 waves/CU (full cap), 729 blocks
// over 1024 slots = one scheduling round, 22-iter point loops.

#define CODE_NUM 64
#define CODE_CHANNEL 64
#define TABLE (CODE_NUM * CODE_NUM * CODE_NUM)  // 262144
#define NBINS 4096                              // 16^3 coarse cells (4-cell bricks)
#define SCAT_PTS 1024                           // points per scatter block
#define SCAT_PPT 4                              // points per thread (1024/256)
#define TBLOCKS (TABLE / 64)                    // 4096 transpose tiles
#define LROW 68                                 // LDS row stride floats (272B pad)

typedef float f4_t __attribute__((ext_vector_type(4)));

__device__ __forceinline__ void nt_store_f4(float* p, float x, float y, float z, float w) {
    f4_t v = {x, y, z, w};
    __builtin_nontemporal_store(v, (f4_t*)p);
}

// ---------------- aux: init ----------------
__global__ __launch_bounds__(256) void init_k(int* __restrict__ hist, int* __restrict__ bbox,
                                              int* __restrict__ done) {
    const int t = blockIdx.x * 256 + threadIdx.x;
    for (int i = t; i < NBINS; i += gridDim.x * 256) hist[i] = 0;
    if (t == 0) {
        bbox[0] = 0x7fffffff; bbox[1] = (int)0x80000000;  // ymin, ymax
        bbox[2] = 0x7fffffff; bbox[3] = (int)0x80000000;  // zmin, zmax
        done[0] = 0;
    }
}

__device__ __forceinline__ int cell_bin(float x, float y, float z,
                                        int& ix, int& iy, int& iz) {
    ix = (int)floorf((x + 1.0f) * ((CODE_NUM - 1) * 0.5f));
    iy = (int)floorf((y + 1.0f) * ((CODE_NUM - 1) * 0.5f));
    iz = (int)floorf((z + 1.0f) * ((CODE_NUM - 1) * 0.5f));
    const int cx = min(max(ix, 0), 63) >> 2;
    const int cy = min(max(iy, 0), 63) >> 2;
    const int cz = min(max(iz, 0), 63) >> 2;
    return cx | (cy << 4) | (cz << 8);
}

// ---------------- pass 1: histogram + bbox; LAST block also does the scan ----------------
__global__ __launch_bounds__(256) void hist_scan_k(const float* __restrict__ coords, int npoints,
                                                   int* __restrict__ hist, int* __restrict__ bbox,
                                                   int* __restrict__ done,
                                                   int* __restrict__ cursor,
                                                   int* __restrict__ starts) {
    __shared__ int lh[NBINS];
    __shared__ int lb[4];
    __shared__ int lastflag;
    __shared__ int wbase[4];
    for (int i = threadIdx.x; i < NBINS; i += 256) lh[i] = 0;
    if (threadIdx.x == 0) {
        lb[0] = 0x7fffffff; lb[1] = (int)0x80000000;
        lb[2] = 0x7fffffff; lb[3] = (int)0x80000000;
        lastflag = 0;
    }
    __syncthreads();
    int ymin = 0x7fffffff, ymax = (int)0x80000000;
    int zmin = 0x7fffffff, zmax = (int)0x80000000;
    const int stride = gridDim.x * 256;
    for (int p = blockIdx.x * 256 + threadIdx.x; p < npoints; p += stride) {
        const float x = coords[p * 3 + 0];
        const float y = coords[p * 3 + 1];
        const float z = coords[p * 3 + 2];
        int ix, iy, iz;
        const int bin = cell_bin(x, y, z, ix, iy, iz);
        atomicAdd(&lh[bin], 1);
        ymin = min(ymin, iy); ymax = max(ymax, iy);
        zmin = min(zmin, iz); zmax = max(zmax, iz);
    }
    atomicMin(&lb[0], ymin); atomicMax(&lb[1], ymax);
    atomicMin(&lb[2], zmin); atomicMax(&lb[3], zmax);
    __syncthreads();
    for (int i = threadIdx.x; i < NBINS; i += 256) {
        const int c = lh[i];
        if (c) atomicAdd(&hist[i], c);
    }
    if (threadIdx.x == 0) {
        atomicMin(&bbox[0], lb[0]); atomicMax(&bbox[1], lb[1]);
        atomicMin(&bbox[2], lb[2]); atomicMax(&bbox[3], lb[3]);
    }
    __threadfence();
    __syncthreads();
    if (threadIdx.x == 0) {
        const int r = atomicAdd(done, 1);
        if (r == (int)gridDim.x - 1) lastflag = 1;
    }
    __syncthreads();
    if (!lastflag) return;

    // ---- scan (only the last-finishing block) ----
    const int t = threadIdx.x;
    int h[16];
    int s = 0;
#pragma unroll
    for (int j = 0; j < 16; ++j) {
        h[j] = atomicAdd(&hist[t * 16 + j], 0);
        s += h[j];
    }
    const int lane = t & 63, wv = t >> 6;
    int inc = s;
#pragma unroll
    for (int d = 1; d < 64; d <<= 1) {
        const int u = __shfl_up(inc, d, 64);
        if (lane >= d) inc += u;
    }
    if (lane == 63) wbase[wv] = inc;
    __syncthreads();
    int wex = 0;
#pragma unroll
    for (int w = 0; w < 4; ++w)
        if (w < wv) wex += wbase[w];
    int run = wex + (inc - s);  // exclusive base for this thread's 16 bins
#pragma unroll
    for (int j = 0; j < 16; ++j) {
        const int bin = t * 16 + j;
        cursor[bin] = run;
        starts[bin] = run;
        run += h[j];
    }
    if (t == 255) starts[NBINS] = npoints;
}

// ---------------- pass 2 (fused): transpose_bb (blocks 0..4095) + scatter (rest) ----------------
__global__ __launch_bounds__(256) void mid_fused_k(const float* __restrict__ src,
                                                   float* __restrict__ dst,
                                                   const int* __restrict__ bbox,
                                                   const float* __restrict__ coords, int npoints,
                                                   int* __restrict__ cursor,
                                                   float4* __restrict__ sorted) {
    __shared__ int smem[64 * 65];

    if (blockIdx.x < TBLOCKS) {
        const int t0 = blockIdx.x * 64;
        const int y = (t0 >> 6) & 63;
        const int z = t0 >> 12;
        if (y < bbox[0] || y > bbox[1] + 1 || z < bbox[2] || z > bbox[3] + 1) return;

        float* tile = (float*)smem;
        const int j = threadIdx.x;
#pragma unroll
        for (int i = 0; i < 4; ++i) {
            const int q = (i << 8) | j;
            const int c = q >> 4;
            const int tc4 = q & 15;
            const float4 v = *(const float4*)(src + (size_t)c * TABLE + t0 + (tc4 << 2));
            tile[((tc4 << 2) + 0) * 65 + c] = v.x;
            tile[((tc4 << 2) + 1) * 65 + c] = v.y;
            tile[((tc4 << 2) + 2) * 65 + c] = v.z;
            tile[((tc4 << 2) + 3) * 65 + c] = v.w;
        }
        __syncthreads();
#pragma unroll
        for (int i = 0; i < 4; ++i) {
            const int q = (i << 8) | j;
            const int t = q >> 4;
            const int c4 = q & 15;
            nt_store_f4(dst + (size_t)(t0 + t) * 64 + (c4 << 2),
                        tile[t * 65 + (c4 << 2) + 0],
                        tile[t * 65 + (c4 << 2) + 1],
                        tile[t * 65 + (c4 << 2) + 2],
                        tile[t * 65 + (c4 << 2) + 3]);
        }
    } else {
        int* lcount = smem;
        for (int i = threadIdx.x; i < NBINS; i += 256) lcount[i] = 0;
        __syncthreads();

        const int p0 = (int)(blockIdx.x - TBLOCKS) * SCAT_PTS;
        float px[SCAT_PPT], py[SCAT_PPT], pz[SCAT_PPT];
        int pbin[SCAT_PPT], prank[SCAT_PPT];

#pragma unroll
        for (int i = 0; i < SCAT_PPT; ++i) {
            const int p = p0 + (i << 8) + (int)threadIdx.x;
            pbin[i] = -1;
            if (p < npoints) {
                const float x = coords[p * 3 + 0];
                const float y = coords[p * 3 + 1];
                const float z = coords[p * 3 + 2];
                int ix, iy, iz;
                const int bin = cell_bin(x, y, z, ix, iy, iz);
                px[i] = x; py[i] = y; pz[i] = z;
                pbin[i] = bin;
                prank[i] = atomicAdd(&lcount[bin], 1);
            }
        }
        __syncthreads();

        for (int i = threadIdx.x; i < NBINS; i += 256) {
            const int c = lcount[i];
            if (c) lcount[i] = atomicAdd(&cursor[i], c);
        }
        __syncthreads();

#pragma unroll
        for (int i = 0; i < SCAT_PPT; ++i) {
            if (pbin[i] >= 0) {
                const int p = p0 + (i << 8) + (int)threadIdx.x;
                const int slot = lcount[pbin[i]] + prank[i];
                sorted[slot] = make_float4(px[i], py[i], pz[i], __int_as_float(p));
            }
        }
    }
}

// ---------------- pass 3: 512-thread block-per-bin interpolation from LDS ----------------
// One block = one bin. Stage its 5x5x5 x 64ch region (32KB, 272B rows) ONCE,
// then 8 waves x 4 points each walk the bin's point range (22-iter loops).
// 34KB LDS -> 4 blocks/CU -> 32 waves/CU (full occupancy cap).
__global__ __launch_bounds__(512) void interp_bin_k(const float4* __restrict__ sorted,
                                                    const float* __restrict__ table,
                                                    const int* __restrict__ starts,
                                                    float* __restrict__ out,
                                                    int npoints) {
    unsigned bid = blockIdx.x;                       // 4096 bins
    bid = (bid & 7u) * (NBINS / 8) + (bid >> 3);     // XCD-chunked swizzle
    const int s = starts[bid];
    const int e = starts[bid + 1];
    if (e <= s) return;

    const int x0 = (bid & 15) << 2;
    const int y0 = ((bid >> 4) & 15) << 2;
    const int z0 = (bid >> 8) << 2;

    __shared__ float lds[125 * LROW];  // 34 KB

    // Stage: 125 rows x 16 float4; src x-contiguous. Boundary bins read a few
    // rows past the region (still inside ws); those values are never consumed.
    const f4_t* tt4 = (const f4_t*)table;
    for (int i = threadIdx.x; i < 125 * 16; i += 512) {
        const int row = i >> 4, o = i & 15;
        const int dx = row % 5;
        const int seg = row / 5;             // dz*5+dy
        const int dy = seg % 5, dz = seg / 5;
        const int cell = (z0 + dz) * (CODE_NUM * CODE_NUM) + (y0 + dy) * CODE_NUM + (x0 + dx);
        *(f4_t*)&lds[row * LROW + (o << 2)] = tt4[(size_t)cell * 16 + o];
    }
    __syncthreads();

    const int lane = threadIdx.x & 63;
    const int wv = threadIdx.x >> 6;     // 0..7
    const int sub = lane >> 4;           // point slot within wave (0..3)
    const int cg = lane & 15;            // channel group

    for (int p = s + wv * 4 + sub; p < e; p += 32) {
        const float4 s4 = sorted[p];
        const int op = __float_as_int(s4.w);

        const float sx = (s4.x + 1.0f) * ((CODE_NUM - 1) * 0.5f);
        const float sy = (s4.y + 1.0f) * ((CODE_NUM - 1) * 0.5f);
        const float sz = (s4.z + 1.0f) * ((CODE_NUM - 1) * 0.5f);
        const float fx = floorf(sx), fy = floorf(sy), fz = floorf(sz);
        const float rx = sx - fx, ry = sy - fy, rz = sz - fz;
        const int ix = (int)fx, iy = (int)fy, iz = (int)fz;
        const int r0 = ((iz - z0) * 5 + (iy - y0)) * 5 + (ix - x0);

        const float wx[2] = {1.0f - rx, rx};
        const float wy[2] = {1.0f - ry, ry};
        const float wz[2] = {1.0f - rz, rz};

        float4 acc = make_float4(0.f, 0.f, 0.f, 0.f);
#pragma unroll
        for (int k = 0; k < 8; ++k) {
            const int a = k & 1, b = (k >> 1) & 1, c = (k >> 2) & 1;
            const int row = r0 + a + 5 * b + 25 * c;
            const float w = wx[a] * wy[b] * wz[c];
            const float4 v = *(const float4*)&lds[row * LROW + (cg << 2)];
            acc.x = fmaf(w, v.x, acc.x);
            acc.y = fmaf(w, v.y, acc.y);
            acc.z = fmaf(w, v.z, acc.z);
            acc.w = fmaf(w, v.w, acc.w);
        }
        nt_store_f4(out + (size_t)op * CODE_CHANNEL + (cg << 2), acc.x, acc.y, acc.z, acc.w);
    }
}

// ---------------- legacy paths (smaller workspace tiers) ----------------
__global__ __launch_bounds__(256) void transpose_k(const float* __restrict__ src,
                                                   float* __restrict__ dst) {
    __shared__ float tile[64 * 65];
    const int t0 = blockIdx.x * 64;
    const int j = threadIdx.x;
#pragma unroll
    for (int i = 0; i < 4; ++i) {
        const int q = (i << 8) | j;
        const int c = q >> 4;
        const int tc4 = q & 15;
        const float4 v = *(const float4*)(src + (size_t)c * TABLE + t0 + (tc4 << 2));
        tile[((tc4 << 2) + 0) * 65 + c] = v.x;
        tile[((tc4 << 2) + 1) * 65 + c] = v.y;
        tile[((tc4 << 2) + 2) * 65 + c] = v.z;
        tile[((tc4 << 2) + 3) * 65 + c] = v.w;
    }
    __syncthreads();
#pragma unroll
    for (int i = 0; i < 4; ++i) {
        const int q = (i << 8) | j;
        const int t = q >> 4;
        const int c4 = q & 15;
        float4 v;
        v.x = tile[t * 65 + (c4 << 2) + 0];
        v.y = tile[t * 65 + (c4 << 2) + 1];
        v.z = tile[t * 65 + (c4 << 2) + 2];
        v.w = tile[t * 65 + (c4 << 2) + 3];
        *(float4*)(dst + (size_t)(t0 + t) * 64 + (c4 << 2)) = v;
    }
}

__global__ __launch_bounds__(256) void interp4_k(const float* __restrict__ coords,
                                                 const float* __restrict__ table,
                                                 const int* __restrict__ idxp,
                                                 float* __restrict__ out,
                                                 int npoints) {
    const unsigned tid = blockIdx.x * 256u + threadIdx.x;
    const int lane = threadIdx.x & 63;
    const int sub = lane >> 4;
    const int cg = lane & 15;
    const int p = (int)((tid >> 6) * 4u + (unsigned)sub);
    if (p >= npoints) return;

    const int offset = idxp[0] * TABLE;
    const float sx = (coords[p * 3 + 0] + 1.0f) * ((CODE_NUM - 1) * 0.5f);
    const float sy = (coords[p * 3 + 1] + 1.0f) * ((CODE_NUM - 1) * 0.5f);
    const float sz = (coords[p * 3 + 2] + 1.0f) * ((CODE_NUM - 1) * 0.5f);
    const float fx = floorf(sx), fy = floorf(sy), fz = floorf(sz);
    const float rx = sx - fx, ry = sy - fy, rz = sz - fz;
    const int ix = (int)fx, iy = (int)fy, iz = (int)fz;
    const int base = offset + ix + iy * CODE_NUM + iz * (CODE_NUM * CODE_NUM);
    const float wx[2] = {1.0f - rx, rx};
    const float wy[2] = {1.0f - ry, ry};
    const float wz[2] = {1.0f - rz, rz};
    const char* tp = (const char*)table;
    const int cgoff = cg << 4;
    float4 acc = make_float4(0.f, 0.f, 0.f, 0.f);
#pragma unroll
    for (int k = 0; k < 8; ++k) {
        const int a = k & 1, b = (k >> 1) & 1, c = (k >> 2) & 1;
        const int idx = base + a + b * CODE_NUM + c * (CODE_NUM * CODE_NUM);
        const float w = wx[a] * wy[b] * wz[c];
        const float4 v = *(const float4*)(tp + ((size_t)(unsigned)(idx << 8) + cgoff));
        acc.x = fmaf(w, v.x, acc.x);
        acc.y = fmaf(w, v.y, acc.y);
        acc.z = fmaf(w, v.z, acc.z);
        acc.w = fmaf(w, v.w, acc.w);
    }
    *(float4*)(out + (size_t)p * CODE_CHANNEL + (cg << 2)) = acc;
}

__global__ __launch_bounds__(256) void interp_fallback_k(const float* __restrict__ coords,
                                                         const float* __restrict__ table,
                                                         const int* __restrict__ idxp,
                                                         float* __restrict__ out,
                                                         int npoints) {
    const int p = (int)((blockIdx.x * 256u + threadIdx.x) >> 6);
    const int lane = threadIdx.x & 63;
    if (p >= npoints) return;
    const int offset = idxp[0] * TABLE;
    const float sx = (coords[p * 3 + 0] + 1.0f) * ((CODE_NUM - 1) * 0.5f);
    const float sy = (coords[p * 3 + 1] + 1.0f) * ((CODE_NUM - 1) * 0.5f);
    const float sz = (coords[p * 3 + 2] + 1.0f) * ((CODE_NUM - 1) * 0.5f);
    const float fx = floorf(sx), fy = floorf(sy), fz = floorf(sz);
    const float rx = sx - fx, ry = sy - fy, rz = sz - fz;
    const int base = offset + (int)fx + (int)fy * CODE_NUM + (int)fz * (CODE_NUM * CODE_NUM);
    const float wx[2] = {1.0f - rx, rx};
    const float wy[2] = {1.0f - ry, ry};
    const float wz[2] = {1.0f - rz, rz};
    float acc = 0.0f;
#pragma unroll
    for (int k = 0; k < 8; ++k) {
        const int a = k & 1, b = (k >> 1) & 1, c = (k >> 2) & 1;
        const int idx = base + a + b * CODE_NUM + c * (CODE_NUM * CODE_NUM);
        acc = fmaf(wx[a] * wy[b] * wz[c], table[(size_t)lane * TABLE + idx], acc);
    }
    out[(size_t)p * CODE_CHANNEL + lane] = acc;
}

extern "C" void kernel_launch(void* const* d_in, const int* in_sizes, int n_in,
                              void* d_out, int out_size, void* d_ws, size_t ws_size,
                              hipStream_t stream) {
    const float* coords = (const float*)d_in[0];
    const float* code   = (const float*)d_in[1];
    const int*   idxp   = (const int*)d_in[2];
    float* out = (float*)d_out;

    const int npoints = in_sizes[0] / 3;  // 524288
    const size_t tbytes = (size_t)TABLE * CODE_CHANNEL * sizeof(float);  // 64 MB
    const size_t sbytes = (size_t)npoints * sizeof(float4);              // 8 MB
    // hist + cursor + starts(+1) + bbox + done, +pad
    const size_t abytes = (size_t)(3 * NBINS + 1 + 4 + 1 + 16) * sizeof(int);
    const size_t need = tbytes + sbytes + abytes;

    if (ws_size >= need) {
        char* w = (char*)d_ws;
        float*  tt     = (float*)w;
        float4* sorted = (float4*)(w + tbytes);
        int*    hist   = (int*)(w + tbytes + sbytes);
        int*    cursor = hist + NBINS;
        int*    starts = cursor + NBINS;
        int*    bbox   = starts + NBINS + 1;
        int*    done   = bbox + 4;

        const int nscat = (npoints + SCAT_PTS - 1) / SCAT_PTS;

        init_k<<<16, 256, 0, stream>>>(hist, bbox, done);
        hist_scan_k<<<128, 256, 0, stream>>>(coords, npoints, hist, bbox, done, cursor, starts);
        mid_fused_k<<<TBLOCKS + nscat, 256, 0, stream>>>(code, tt, bbox,
                                                         coords, npoints, cursor, sorted);
        interp_bin_k<<<NBINS, 512, 0, stream>>>(sorted, tt, starts, out, npoints);
    } else if (ws_size >= tbytes) {
        float* tt = (float*)d_ws;
        transpose_k<<<TABLE / 64, 256, 0, stream>>>(code, tt);
        interp4_k<<<(npoints + 15) / 16, 256, 0, stream>>>(coords, tt, idxp, out, npoints);
    } else {
        interp_fallback_k<<<(npoints + 3) / 4, 256, 0, stream>>>(coords, code, idxp, out, npoints);
    }
}